// Round 2
// baseline (120.765 us; speedup 1.0000x reference)
//
#include <hip/hip_runtime.h>

typedef _Float16 half4v __attribute__((ext_vector_type(4)));
typedef _Float16 h2     __attribute__((ext_vector_type(2)));
typedef float    float4v __attribute__((ext_vector_type(4)));

#define BB 16
#define CC 64
#define NN 4096   // H*W
#define MM 1024   // H*W/4
#define LN256 5.545177444479562f

static __device__ __forceinline__ float4v mfma16(half4v a, half4v b, float4v c) {
    return __builtin_amdgcn_mfma_f32_16x16x16f16(a, b, c, 0, 0, 0);
}

// fp32 pair -> packed fp16 pair (as u32)
__device__ __forceinline__ unsigned pk2(float a, float b) {
    union { _Float16 h[2]; unsigned u; } cv;
    cv.h[0] = (_Float16)a; cv.h[1] = (_Float16)b;
    return cv.u;
}
__device__ __forceinline__ h2 ash2(unsigned u) {
    union { unsigned u; h2 h; } c; c.u = u; return c.h;
}
__device__ __forceinline__ h2 hmax2(h2 a, h2 b) {
    h2 r;
    r.x = (a.x > b.x) ? a.x : b.x;
    r.y = (a.y > b.y) ? a.y : b.y;
    return r;
}
__device__ __forceinline__ h2 shfl_xor_h2(h2 v, int m) {
    union { h2 h; int i; } c; c.h = v; c.i = __shfl_xor(c.i, m);
    return c.h;
}

// gT LDS swizzle: [32][1024] fp16, no pad (64 KB exactly).
// byte = c*2048 + m*2, XOR nibble ((c ^ (m>>6)) & 15) << 3:
//  - reads (c=col per lane, m>>6 uniform per instr): 16 distinct banks per
//    16-lane phase -> conflict-free ds_read_b64
//  - keeps 8-byte blocks intact (XOR bits 3..6), bijective within each row
__device__ __forceinline__ int gl_off(int c, int m) {
    return (c * 2048 + m * 2) ^ (((c ^ (m >> 6)) & 15) << 3);
}

// ---------------------------------------------------------------------------
// Kernel 1 (unchanged, R10-proven): projections + fused 2x2 maxpool.
//   z=0: theta [B][N][8] + phi [B][M][8] (fp32 accum)
//   z=1: gT [B][32][M] via packed fp16 weights + v_pk_fma_f16
// ---------------------------------------------------------------------------
__global__ __launch_bounds__(128, 4) void proj_kernel(
    const float* __restrict__ x,      // [B][C][N]
    const float* __restrict__ w_th,   // [8][64]
    const float* __restrict__ w_ph,   // [8][64]
    const float* __restrict__ w_g,    // [32][64]
    _Float16* __restrict__ theta,     // [B][N][8]
    _Float16* __restrict__ phi,       // [B][M][8]
    _Float16* __restrict__ gT)        // [B][32][M]
{
    __shared__ __align__(16) float wlds[64 * 16];   // 4 KB (z1 reuses as u32)
    unsigned* wl2 = (unsigned*)wlds;

    const int b   = blockIdx.y;
    const int blk = blockIdx.x;
    const int z   = blockIdx.z;
    const int t   = threadIdx.x;

    if (z == 0) {
        for (int i = t; i < 1024; i += 128) {       // [c][o]: o<8 th, o<16 ph
            int c = i >> 4, o = i & 15;
            wlds[i] = (o < 8) ? w_th[o * 64 + c] : w_ph[(o - 8) * 64 + c];
        }
    } else {
        for (int i = t; i < 1024; i += 128) {       // [c][o2] h2 channel-pairs
            int c = i >> 4, o2 = i & 15;
            wl2[i] = pk2(w_g[(2 * o2) * 64 + c], w_g[(2 * o2 + 1) * 64 + c]);
        }
    }
    __syncthreads();

    const float2* x2 = (const float2*)(x + (size_t)b * CC * NN);
    const int p2 = blk * 128 + t;
    const int l = t & 63, w = t >> 6;
    const int m = (blk * 2 + w) * 32 + (l & 31);

    if (z == 0) {
        float th0[8], th1[8], ph0[8], ph1[8];
#pragma unroll
        for (int i = 0; i < 8; i++) { th0[i]=th1[i]=ph0[i]=ph1[i]=0.f; }
#pragma unroll 4
        for (int c = 0; c < 64; c++) {
            float2 xv = x2[c * (NN / 2) + p2];
            const float4* w4 = (const float4*)&wlds[c * 16];
            float4 wv[4];
#pragma unroll
            for (int j = 0; j < 4; j++) wv[j] = w4[j];
            const float* wf = (const float*)wv;
#pragma unroll
            for (int o = 0; o < 8; o++) {
                th0[o] = fmaf(wf[o], xv.x, th0[o]);
                th1[o] = fmaf(wf[o], xv.y, th1[o]);
                ph0[o] = fmaf(wf[8 + o], xv.x, ph0[o]);
                ph1[o] = fmaf(wf[8 + o], xv.y, ph1[o]);
            }
        }
        uint4* tw = (uint4*)(theta + ((size_t)b * NN + 2 * p2) * 8);
        tw[0] = make_uint4(pk2(th0[0],th0[1]), pk2(th0[2],th0[3]),
                           pk2(th0[4],th0[5]), pk2(th0[6],th0[7]));
        tw[1] = make_uint4(pk2(th1[0],th1[1]), pk2(th1[2],th1[3]),
                           pk2(th1[4],th1[5]), pk2(th1[6],th1[7]));
        float phm[8];
#pragma unroll
        for (int i = 0; i < 8; i++) phm[i] = fmaxf(ph0[i], ph1[i]);
#pragma unroll
        for (int i = 0; i < 8; i++) phm[i] = fmaxf(phm[i], __shfl_xor(phm[i], 32));
        if (l < 32) {
            uint4* pw = (uint4*)(phi + ((size_t)b * MM + m) * 8);
            pw[0] = make_uint4(pk2(phm[0],phm[1]), pk2(phm[2],phm[3]),
                               pk2(phm[4],phm[5]), pk2(phm[6],phm[7]));
        }
    } else {
        h2 ga[16], gb[16];
#pragma unroll
        for (int i = 0; i < 16; i++) { ga[i] = (h2)0; gb[i] = (h2)0; }
#pragma unroll 4
        for (int c = 0; c < 64; c++) {
            float2 xv = x2[c * (NN / 2) + p2];
            const uint4* w4 = (const uint4*)&wl2[c * 16];
            uint4 q0 = w4[0], q1 = w4[1], q2 = w4[2], q3 = w4[3];
            unsigned wv[16] = {q0.x,q0.y,q0.z,q0.w, q1.x,q1.y,q1.z,q1.w,
                               q2.x,q2.y,q2.z,q2.w, q3.x,q3.y,q3.z,q3.w};
            _Float16 hx = (_Float16)xv.x, hy = (_Float16)xv.y;
            h2 xa; xa.x = hx; xa.y = hx;
            h2 xb; xb.x = hy; xb.y = hy;
#pragma unroll
            for (int k = 0; k < 16; k++) {
                ga[k] = __builtin_elementwise_fma(ash2(wv[k]), xa, ga[k]);
                gb[k] = __builtin_elementwise_fma(ash2(wv[k]), xb, gb[k]);
            }
        }
        h2 gm[16];
#pragma unroll
        for (int k = 0; k < 16; k++) gm[k] = hmax2(ga[k], gb[k]);
#pragma unroll
        for (int k = 0; k < 16; k++) gm[k] = hmax2(gm[k], shfl_xor_h2(gm[k], 32));
        const int k0 = (l < 32) ? 0 : 8;
        _Float16* gp = gT + ((size_t)b * 32 + 2 * k0) * MM + m;
#pragma unroll
        for (int k = 0; k < 8; k++) {
            h2 v = gm[k0 + k];
            gp[(size_t)(2 * k) * MM]     = v.x;
            gp[(size_t)(2 * k + 1) * MM] = v.y;
        }
    }
}

// ---------------------------------------------------------------------------
// Kernel 2 (R13, resubmitted after infra failure): barrier-free two-pass
// MFMA attention. ALL of phi[b] (16 KB) AND all of gT[b] (64 KB) persist in
// LDS -> the pass-2 loop has ZERO barriers (previously 8 chunk barriers,
// each draining the staging loads: the m97 barrier-stall pattern).
// 512-thread blocks (8 waves x 16 n): 80 KB LDS -> exactly 2 blocks/CU = 16
// waves/CU (same as before), but half the L2 staging traffic per n-column
// and one residency round (512 blocks). gT global loads are issued before
// barrier 1 and written to LDS after pass 1 (latency hidden under the 64
// max-MFMAs). XOR swizzles replace padding: phl byte ^= (m&8), gl byte ^=
// ((c^(m>>6))&15)<<3 -> ds_read_b64 conflict-free per 16-lane phase, arrays
// stay power-of-2 so 2x80 KB fits. Math identical to R10 -> same absmax.
// ---------------------------------------------------------------------------
__global__ __launch_bounds__(512, 4) void attn_kernel(
    const _Float16* __restrict__ theta,  // [B][N][8]
    const _Float16* __restrict__ phi,    // [B][M][8]
    const _Float16* __restrict__ gT,     // [B][32][M]
    const float* __restrict__ w_o,       // [64][32]
    const float* __restrict__ gamma_p,
    const float* __restrict__ x,         // [B][C][N]
    float* __restrict__ out)             // [B][C][N]
{
    __shared__ __align__(16) _Float16 phl[MM * 8];   // 16 KB, all of phi[b]
    __shared__ __align__(16) _Float16 gl[32 * MM];   // 64 KB, all of gT[b]

    const int b    = blockIdx.y;
    const int t    = threadIdx.x;
    const int wave = t >> 6;
    const int lane = t & 63;
    const int col  = lane & 15;       // n-col / c-row / co-row of frags
    const int q    = lane >> 4;       // quad
    const int nbase = blockIdx.x * 128 + wave * 16;

    const float4v zero4 = {0.f, 0.f, 0.f, 0.f};
    const half4v zeroh = {0, 0, 0, 0};

    // ---- issue ALL staging loads up front (coalesced float4) ----
    const float4* ph4 = (const float4*)(phi + (size_t)b * MM * 8);
    const float4* gt4 = (const float4*)(gT + (size_t)b * 32 * MM);
    float4 pr0 = ph4[t], pr1 = ph4[t + 512];
    float4 gr[8];
#pragma unroll
    for (int j = 0; j < 8; j++) gr[j] = gt4[t + j * 512];

    // theta B-frag for this wave's 16 n (k = q*4+j; k>=8 is zero pad)
    half4v thB = zeroh;
    if (q < 2)
        thB = *(const half4v*)(theta + ((size_t)b * NN + nbase + col) * 8 + q * 4);

    // ones A-frag: output row 0 = softmax denominator
    half4v onesA = zeroh;
    if (col == 0) {
        onesA[0] = (_Float16)1; onesA[1] = (_Float16)1;
        onesA[2] = (_Float16)1; onesA[3] = (_Float16)1;
    }

    // ---- write phi to LDS (swizzled) ----
    char* phb = (char*)phl;
    {
        int m = t;               // float4 index == m-row
        *(float2*)(phb + ((m * 16)     ^ (m & 8))) = *(const float2*)&pr0;
        *(float2*)(phb + ((m * 16 + 8) ^ (m & 8))) = *((const float2*)&pr0 + 1);
        m = t + 512;
        *(float2*)(phb + ((m * 16)     ^ (m & 8))) = *(const float2*)&pr1;
        *(float2*)(phb + ((m * 16 + 8) ^ (m & 8))) = *((const float2*)&pr1 + 1);
    }
    __syncthreads();

    // ---- pass 1: exact per-column score max (barrier-free; gT loads in
    //      flight underneath) ----
    float mx = -1e30f;
#pragma unroll 4
    for (int mt = 0; mt < 64; mt++) {
        half4v af = zeroh;
        if (q < 2) {
            int m = mt * 16 + col;
            af = *(const half4v*)(phb + ((m * 16 + q * 8) ^ (m & 8)));
        }
        float4v S = mfma16(af, thB, zero4);
        mx = fmaxf(mx, fmaxf(fmaxf(S.x, S.y), fmaxf(S.z, S.w)));
    }
    // reduce across the 4 quads that hold the same column (lane bits 4,5)
    mx = fmaxf(mx, __shfl_xor(mx, 16));
    mx = fmaxf(mx, __shfl_xor(mx, 32));
    const float shift = mx - LN256;   // P = e^(s-mx) * 256 <= 256

    // ---- write gT to LDS (swizzled) ----
    char* glb = (char*)gl;
#pragma unroll
    for (int j = 0; j < 8; j++) {
        int idx4 = t + j * 512;
        int c = idx4 >> 7;              // 128 float4 per row
        int m = (idx4 & 127) * 8;
        *(float2*)(glb + gl_off(c, m))     = *(const float2*)&gr[j];
        *(float2*)(glb + gl_off(c, m + 4)) = *((const float2*)&gr[j] + 1);
    }
    __syncthreads();

    // ---- pass 2: P, O^T, denominator — zero barriers ----
    float4v acc0 = zero4, acc1 = zero4, accd = zero4;
#pragma unroll 4
    for (int mt = 0; mt < 64; mt++) {
        half4v af = zeroh;
        if (q < 2) {
            int m = mt * 16 + col;
            af = *(const half4v*)(phb + ((m * 16 + q * 8) ^ (m & 8)));
        }
        float4v S = mfma16(af, thB, zero4);
        // S^T[m = mt*16 + q*4 + r][n = nbase + col]
        half4v P;
        P[0] = (_Float16)__expf(S.x - shift);
        P[1] = (_Float16)__expf(S.y - shift);
        P[2] = (_Float16)__expf(S.z - shift);
        P[3] = (_Float16)__expf(S.w - shift);
        // A-frags of gT: row = c-local = col, k = m-local = q*4+j
        const int m0 = mt * 16 + q * 4;
        half4v ag0 = *(const half4v*)(glb + gl_off(col,      m0));
        half4v ag1 = *(const half4v*)(glb + gl_off(col + 16, m0));
        acc0 = mfma16(ag0, P, acc0);   // O^T c 0-15
        acc1 = mfma16(ag1, P, acc1);   // O^T c 16-31
        accd = mfma16(onesA, P, accd); // row 0 = denominator
    }

    // denominator: accd row 0 lives on lanes 0-15 (q==0), element .x
    float dv = __shfl(accd.x, col);            // den[n] broadcast to all quads
    float sc = gamma_p[0] / dv;                // fold gamma into the scale

    // normalized O^T as B-frags for the w_o MFMA
    half4v B0, B1;
    B0[0] = (_Float16)(acc0.x * sc); B0[1] = (_Float16)(acc0.y * sc);
    B0[2] = (_Float16)(acc0.z * sc); B0[3] = (_Float16)(acc0.w * sc);
    B1[0] = (_Float16)(acc1.x * sc); B1[1] = (_Float16)(acc1.y * sc);
    B1[2] = (_Float16)(acc1.z * sc); B1[3] = (_Float16)(acc1.w * sc);

#pragma unroll
    for (int ct = 0; ct < 4; ct++) {
        // w_o A-frags: row = co-local = col, k = c = half*16 + q*4+j
        const float* wp = w_o + (size_t)(ct * 16 + col) * 32 + q * 4;
        float4 w0 = *(const float4*)wp;           // c 0-15 part
        float4 w1 = *(const float4*)(wp + 16);    // c 16-31 part
        half4v wa, wb;
        wa[0] = (_Float16)w0.x; wa[1] = (_Float16)w0.y;
        wa[2] = (_Float16)w0.z; wa[3] = (_Float16)w0.w;
        wb[0] = (_Float16)w1.x; wb[1] = (_Float16)w1.y;
        wb[2] = (_Float16)w1.z; wb[3] = (_Float16)w1.w;
        float4v D = mfma16(wa, B0, zero4);
        D = mfma16(wb, B1, D);
        // D[co-local = q*4+r][n = col]; out = D + x (gamma already in sc)
#pragma unroll
        for (int r = 0; r < 4; r++) {
            int co = ct * 16 + q * 4 + r;
            size_t idx = ((size_t)b * CC + co) * NN + nbase + col;
            out[idx] = D[r] + x[idx];
        }
    }
}

extern "C" void kernel_launch(void* const* d_in, const int* in_sizes, int n_in,
                              void* d_out, int out_size, void* d_ws, size_t ws_size,
                              hipStream_t stream) {
    const float* x       = (const float*)d_in[0];
    const float* w_theta = (const float*)d_in[1];
    const float* w_phi   = (const float*)d_in[2];
    const float* w_g     = (const float*)d_in[3];
    const float* w_o     = (const float*)d_in[4];
    const float* gamma   = (const float*)d_in[5];
    float* out = (float*)d_out;

    // fp16 workspace: theta [B][N][8], phi [B][M][8], gT [B][32][M] = 2.4 MB
    _Float16* theta_ws = (_Float16*)d_ws;
    _Float16* phi_ws   = theta_ws + (size_t)BB * NN * 8;
    _Float16* gT_ws    = phi_ws   + (size_t)BB * MM * 8;

    proj_kernel<<<dim3(16, BB, 2), 128, 0, stream>>>(
        x, w_theta, w_phi, w_g, theta_ws, phi_ws, gT_ws);

    attn_kernel<<<dim3(NN / 128, BB), 512, 0, stream>>>(
        theta_ws, phi_ws, gT_ws, w_o, gamma, x, out);
}